// Round 6
// baseline (395.849 us; speedup 1.0000x reference)
//
#include <hip/hip_runtime.h>
#include <hip/hip_bf16.h>

// CrossAttention: B=4, Tv=8192, Tt=77, C=1024, H=16, D=64
// q = video@Wq.T ; k,v = text@W{k,v}.T ; softmax(qk^T/8)v ; out = attn@Wo.T
// Round 5: 256x256 8-phase counted-vmcnt GEMM (T2+T3+T4+T5) for q-proj and o-proj.

typedef __attribute__((ext_vector_type(8))) short bf16x8;
typedef __attribute__((ext_vector_type(4))) float f32x4;
typedef __attribute__((ext_vector_type(8))) unsigned short u16x8;
typedef __attribute__((ext_vector_type(4))) unsigned short u16x4;

typedef const __attribute__((address_space(1))) void gv_t;
typedef __attribute__((address_space(3))) void lv_t;

static __device__ __forceinline__ unsigned short f2bf(float f) {
    union { float f; unsigned u; } v; v.f = f;
    unsigned r = v.u + 0x7FFFu + ((v.u >> 16) & 1u);  // RNE
    return (unsigned short)(r >> 16);
}

constexpr int Bn = 4, TVn = 8192, TTn = 77, Cn = 1024, Hn = 16;

// ---------------- fp32 -> bf16 convert, 8 elems/thread ----------------
__global__ void k_cvt8(const float* __restrict__ in, unsigned short* __restrict__ out, int n8) {
    int i = blockIdx.x * 256 + threadIdx.x;
    if (i >= n8) return;
    const float4* p = reinterpret_cast<const float4*>(in) + (size_t)i * 2;
    float4 a = p[0], b = p[1];
    u16x8 o = { f2bf(a.x), f2bf(a.y), f2bf(a.z), f2bf(a.w),
                f2bf(b.x), f2bf(b.y), f2bf(b.z), f2bf(b.w) };
    *reinterpret_cast<u16x8*>(out + (size_t)i * 8) = o;
}

// ---- stage one K-half-tile: 256 rows x 32 cols bf16 into a [256][32] LDS block ----
// Linear LDS dest (global_load_lds), inverse-swizzled global source: LDS[r][s] = G[r][s^((r>>1)&3)]
__device__ __forceinline__ void stage_half(const unsigned short* __restrict__ src,
                                           int t0, int kcol0,
                                           unsigned short* lds, int tid) {
    const int lane = tid & 63, w = tid >> 6;
    #pragma unroll
    for (int j = 0; j < 2; ++j) {
        const int lrow = j * 128 + w * 16 + (lane >> 2);
        const int sseg = (lane & 3) ^ ((lrow >> 1) & 3);
        const unsigned short* g = src + (size_t)(t0 + lrow) * 1024 + kcol0 + sseg * 8;
        __builtin_amdgcn_global_load_lds((gv_t*)g, (lv_t*)(lds + (j * 128 + w * 16) * 32), 16, 0, 0);
    }
}

// ---------------- 256x256x(K=1024) bf16 GEMM, 8-phase schedule, counted vmcnt ----------------
// A [32768][1024] bf16 row-major; W [1024][1024] bf16 row-major (C = A @ W^T).
template<int OUT_BF16>
__global__ __launch_bounds__(512, 2)
void k_gemm256(const unsigned short* __restrict__ A, const unsigned short* __restrict__ Wb,
               void* __restrict__ outp) {
    __shared__ unsigned short As[2][2][256][32];   // [buf][khalf][row][col] 64 KiB
    __shared__ unsigned short Bs[2][2][256][32];   // 64 KiB
    const int tid = threadIdx.x, lane = tid & 63, wid = tid >> 6;
    const int wm = wid >> 2, wn = wid & 3;          // 2 x 4 wave grid
    const int orig = blockIdx.x;
    const int work = (orig & 7) * 64 + (orig >> 3);  // bijective XCD swizzle (512 % 8 == 0)
    const int m0 = (work >> 2) * 256, n0 = (work & 3) * 256;
    const int lr = lane & 15, lg = lane >> 4;

    f32x4 acc[8][4] = {};

    // prologue: stage Kh0(t0), Kh1(t0), Kh0(t1); wait first two K-halves (tile 0 complete)
    stage_half(A,  m0, 0,  &As[0][0][0][0], tid);
    stage_half(Wb, n0, 0,  &Bs[0][0][0][0], tid);
    stage_half(A,  m0, 32, &As[0][1][0][0], tid);
    stage_half(Wb, n0, 32, &Bs[0][1][0][0], tid);
    stage_half(A,  m0, 64, &As[1][0][0][0], tid);
    stage_half(Wb, n0, 64, &Bs[1][0][0][0], tid);
    asm volatile("s_waitcnt vmcnt(4)" ::: "memory");   // tile 0 (8 loads) landed; Kh0(1) may fly
    __builtin_amdgcn_s_barrier();

    for (int t = 0; t < 16; ++t) {
        const int b = t & 1;
        #pragma unroll
        for (int ph = 0; ph < 4; ++ph) {
            const int ks = ph >> 1, mh = ph & 1;    // quadrant: (K-half, M-half)
            bf16x8 af[4], bg[4];
            #pragma unroll
            for (int m4 = 0; m4 < 4; ++m4) {
                const int rA = wm * 128 + mh * 64 + m4 * 16 + lr;
                af[m4] = *reinterpret_cast<const bf16x8*>(
                    &As[b][ks][rA][(lg ^ ((rA >> 1) & 3)) * 8]);
            }
            #pragma unroll
            for (int n4 = 0; n4 < 4; ++n4) {
                const int rB = wn * 64 + n4 * 16 + lr;
                bg[n4] = *reinterpret_cast<const bf16x8*>(
                    &Bs[b][ks][rB][(lg ^ ((rB >> 1) & 3)) * 8]);
            }
            // staging stream: each target region was freed at the previous phase's end barrier
            if (ph == 0 && t + 1 < 16) stage_half(A,  m0, (t + 1) * 64 + 32, &As[b ^ 1][1][0][0], tid);
            if (ph == 1 && t + 1 < 16) stage_half(Wb, n0, (t + 1) * 64 + 32, &Bs[b ^ 1][1][0][0], tid);
            if (ph == 2 && t + 2 < 16) stage_half(A,  m0, (t + 2) * 64,      &As[b][0][0][0], tid);
            if (ph == 3 && t + 2 < 16) stage_half(Wb, n0, (t + 2) * 64,      &Bs[b][0][0][0], tid);
            __builtin_amdgcn_s_barrier();
            asm volatile("s_waitcnt lgkmcnt(0)" ::: "memory");
            __builtin_amdgcn_sched_barrier(0);
            __builtin_amdgcn_s_setprio(1);
            #pragma unroll
            for (int m4 = 0; m4 < 4; ++m4)
                #pragma unroll
                for (int n4 = 0; n4 < 4; ++n4)
                    acc[mh * 4 + m4][n4] = __builtin_amdgcn_mfma_f32_16x16x32_bf16(
                        af[m4], bg[n4], acc[mh * 4 + m4][n4], 0, 0, 0);
            __builtin_amdgcn_s_setprio(0);
            if (ph == 3) {
                if (t < 14) { asm volatile("s_waitcnt vmcnt(4)" ::: "memory"); }
                else        { asm volatile("s_waitcnt vmcnt(0)" ::: "memory"); }
            }
            __builtin_amdgcn_s_barrier();
        }
    }

    #pragma unroll
    for (int mf = 0; mf < 8; ++mf)
        #pragma unroll
        for (int nf = 0; nf < 4; ++nf)
            #pragma unroll
            for (int r = 0; r < 4; ++r) {
                int grow = m0 + wm * 128 + mf * 16 + lg * 4 + r;
                int gcol = n0 + wn * 64 + nf * 16 + lr;
                if (OUT_BF16) {
                    unsigned short bv = f2bf(acc[mf][nf][r]);
                    unsigned ov = __shfl_xor((unsigned)bv, 1);
                    if (!(lane & 1)) {
                        unsigned short* out = (unsigned short*)outp;
                        *reinterpret_cast<unsigned*>(out + (size_t)grow * 1024 + gcol) =
                            (unsigned)bv | (ov << 16);
                    }
                } else {
                    float v = acc[mf][nf][r];
                    float o = __shfl_xor(v, 1);
                    if (!(lane & 1)) {
                        float* out = (float*)outp;
                        float2 pv; pv.x = v; pv.y = o;
                        *reinterpret_cast<float2*>(out + (size_t)grow * 1024 + gcol) = pv;
                    }
                }
            }
}

// ---------------- K/V projection: A fp32 [M][1024] @ W fp32 [1024][1024]^T -> bf16 ----------------
__global__ __launch_bounds__(256)
void k_gemm_kv(const float* __restrict__ A, const float* __restrict__ W0,
               const float* __restrict__ W1, unsigned short* __restrict__ o0,
               unsigned short* __restrict__ o1, int M) {
    const float* W = blockIdx.z ? W1 : W0;
    unsigned short* out = blockIdx.z ? o1 : o0;
    __shared__ unsigned short As[128 * 32];
    __shared__ unsigned short Bs[128 * 32];
    const int tid = threadIdx.x, lane = tid & 63, wv = tid >> 6;
    const int m0 = blockIdx.x * 128, n0 = blockIdx.y * 128;
    const int wr = (wv >> 1) * 64, wc = (wv & 1) * 64;
    const int lr = lane & 15, lk = (lane >> 4) * 8, lg = lane >> 4;
    f32x4 acc[4][4] = {};
    for (int kk = 0; kk < 1024; kk += 32) {
        #pragma unroll
        for (int it = 0; it < 4; ++it) {
            int li = it * 256 + tid;
            int row = li >> 3, c4 = (li & 7) * 4;
            int gr = m0 + row;
            float4 v = make_float4(0.f, 0.f, 0.f, 0.f);
            if (gr < M) v = *reinterpret_cast<const float4*>(A + (size_t)gr * 1024 + kk + c4);
            u16x4 o = { f2bf(v.x), f2bf(v.y), f2bf(v.z), f2bf(v.w) };
            *reinterpret_cast<u16x4*>(&As[row * 32 + c4]) = o;
        }
        #pragma unroll
        for (int it = 0; it < 4; ++it) {
            int li = it * 256 + tid;
            int row = li >> 3, c4 = (li & 7) * 4;
            float4 v = *reinterpret_cast<const float4*>(W + (size_t)(n0 + row) * 1024 + kk + c4);
            u16x4 o = { f2bf(v.x), f2bf(v.y), f2bf(v.z), f2bf(v.w) };
            *reinterpret_cast<u16x4*>(&Bs[row * 32 + c4]) = o;
        }
        __syncthreads();
        bf16x8 af[4], bfv[4];
        #pragma unroll
        for (int m = 0; m < 4; ++m)
            af[m] = *reinterpret_cast<const bf16x8*>(&As[(wr + m * 16 + lr) * 32 + lk]);
        #pragma unroll
        for (int n = 0; n < 4; ++n)
            bfv[n] = *reinterpret_cast<const bf16x8*>(&Bs[(wc + n * 16 + lr) * 32 + lk]);
        #pragma unroll
        for (int m = 0; m < 4; ++m)
            #pragma unroll
            for (int n = 0; n < 4; ++n)
                acc[m][n] = __builtin_amdgcn_mfma_f32_16x16x32_bf16(af[m], bfv[n], acc[m][n], 0, 0, 0);
        __syncthreads();
    }
    #pragma unroll
    for (int m = 0; m < 4; ++m)
        #pragma unroll
        for (int n = 0; n < 4; ++n)
            #pragma unroll
            for (int r = 0; r < 4; ++r) {
                int grow = m0 + wr + m * 16 + lg * 4 + r;
                if (grow < M) {
                    int gcol = n0 + wc + n * 16 + lr;
                    out[(size_t)grow * 1024 + gcol] = f2bf(acc[m][n][r]);
                }
            }
}

// ---------------- attention v2: 128 q-rows x 1 head per block; direct global frags; 1 barrier ----
__global__ __launch_bounds__(256)
void k_attn2(unsigned short* __restrict__ q,        // [32768][1024] bf16, attn written in-place
             const unsigned short* __restrict__ kb, // [308][1024]
             const unsigned short* __restrict__ vb) {
    constexpr int VP = 104, PP = 104;               // 2-way-bank strides, 16B-aligned rows
    __shared__ unsigned short vt_s[64 * VP];        // 13312 B  V^T tile
    __shared__ unsigned short p_s[128 * PP];        // 26624 B  P (wave-private rows)
    const int tid = threadIdx.x, lane = tid & 63, wv = tid >> 6;
    const int m0 = blockIdx.x * 128;
    const int h = blockIdx.y, b = blockIdx.z;
    const size_t qbase = ((size_t)b * TVn + m0) * Cn + h * 64;
    const size_t kvbase = (size_t)b * TTn * Cn + h * 64;
    const int lr = lane & 15, lg = lane >> 4;

    for (int li = tid; li < 80 * 64; li += 256) {
        int t = li >> 6, d = li & 63;
        unsigned short v = 0;
        if (t < 77) v = vb[kvbase + (size_t)t * Cn + d];
        vt_s[d * VP + t] = v;
    }
    for (int li = tid; li < 64 * 16; li += 256) {
        int d = li >> 4, t = 80 + (li & 15);
        vt_s[d * VP + t] = 0;
    }

    f32x4 sc[2][5] = {};
    #pragma unroll
    for (int ks = 0; ks < 2; ++ks) {
        bf16x8 qa[2], kf[5];
        #pragma unroll
        for (int mf = 0; mf < 2; ++mf)
            qa[mf] = *reinterpret_cast<const bf16x8*>(
                q + qbase + (size_t)(wv * 32 + mf * 16 + lr) * Cn + ks * 32 + lg * 8);
        #pragma unroll
        for (int nf = 0; nf < 5; ++nf) {
            int t = nf * 16 + lr; if (t > 76) t = 76;
            kf[nf] = *reinterpret_cast<const bf16x8*>(
                kb + kvbase + (size_t)t * Cn + ks * 32 + lg * 8);
        }
        #pragma unroll
        for (int mf = 0; mf < 2; ++mf)
            #pragma unroll
            for (int nf = 0; nf < 5; ++nf)
                sc[mf][nf] = __builtin_amdgcn_mfma_f32_16x16x32_bf16(qa[mf], kf[nf], sc[mf][nf], 0, 0, 0);
    }

    float pr[2][5][4];
    float rs[2][4];
    #pragma unroll
    for (int mf = 0; mf < 2; ++mf) {
        #pragma unroll
        for (int r = 0; r < 4; ++r) {
            float mx = -1e30f;
            #pragma unroll
            for (int nf = 0; nf < 5; ++nf) {
                float s = sc[mf][nf][r];
                if (nf * 16 + lr >= 77) s = -1e30f;
                pr[mf][nf][r] = s;
                mx = fmaxf(mx, s);
            }
            #pragma unroll
            for (int x = 1; x < 16; x <<= 1) mx = fmaxf(mx, __shfl_xor(mx, x));
            float sum = 0.f;
            #pragma unroll
            for (int nf = 0; nf < 5; ++nf) {
                float p = (pr[mf][nf][r] > -1e29f) ? __expf((pr[mf][nf][r] - mx) * 0.125f) : 0.f;
                pr[mf][nf][r] = p;
                sum += p;
            }
            #pragma unroll
            for (int x = 1; x < 16; x <<= 1) sum += __shfl_xor(sum, x);
            rs[mf][r] = 1.f / sum;
        }
    }

    for (int li = lane; li < 512; li += 64) {
        int rr = wv * 32 + (li >> 4);
        p_s[rr * PP + 80 + (li & 15)] = 0;
    }
    #pragma unroll
    for (int mf = 0; mf < 2; ++mf)
        #pragma unroll
        for (int r = 0; r < 4; ++r)
            #pragma unroll
            for (int nf = 0; nf < 5; ++nf)
                p_s[(wv * 32 + mf * 16 + lg * 4 + r) * PP + nf * 16 + lr] = f2bf(pr[mf][nf][r]);

    __syncthreads();

    f32x4 ovv[2][4] = {};
    #pragma unroll
    for (int ks = 0; ks < 3; ++ks) {
        bf16x8 pa[2], vf[4];
        #pragma unroll
        for (int mf = 0; mf < 2; ++mf)
            pa[mf] = *reinterpret_cast<const bf16x8*>(
                &p_s[(wv * 32 + mf * 16 + lr) * PP + ks * 32 + lg * 8]);
        #pragma unroll
        for (int nf = 0; nf < 4; ++nf)
            vf[nf] = *reinterpret_cast<const bf16x8*>(
                &vt_s[(nf * 16 + lr) * VP + ks * 32 + lg * 8]);
        #pragma unroll
        for (int mf = 0; mf < 2; ++mf)
            #pragma unroll
            for (int nf = 0; nf < 4; ++nf)
                ovv[mf][nf] = __builtin_amdgcn_mfma_f32_16x16x32_bf16(pa[mf], vf[nf], ovv[mf][nf], 0, 0, 0);
    }
    #pragma unroll
    for (int mf = 0; mf < 2; ++mf)
        #pragma unroll
        for (int nf = 0; nf < 4; ++nf)
            #pragma unroll
            for (int r = 0; r < 4; ++r) {
                float v = ovv[mf][nf][r] * rs[mf][r];
                unsigned short bv = f2bf(v);
                unsigned o = __shfl_xor((unsigned)bv, 1);
                if (!(lane & 1)) {
                    int row = m0 + wv * 32 + mf * 16 + lg * 4 + r;
                    int col = h * 64 + nf * 16 + lr;
                    *reinterpret_cast<unsigned*>(q + ((size_t)b * TVn + row) * Cn + col) =
                        (unsigned)bv | (o << 16);
                }
            }
}

extern "C" void kernel_launch(void* const* d_in, const int* in_sizes, int n_in,
                              void* d_out, int out_size, void* d_ws, size_t ws_size,
                              hipStream_t stream) {
    const float* video = (const float*)d_in[0];
    const float* text  = (const float*)d_in[1];
    const float* Wq = (const float*)d_in[2];
    const float* Wk = (const float*)d_in[3];
    const float* Wv = (const float*)d_in[4];
    const float* Wo = (const float*)d_in[5];
    float* out = (float*)d_out;

    char* ws = (char*)d_ws;
    unsigned short* wq_b = (unsigned short*)(ws);                    // 2 MiB
    unsigned short* wo_b = (unsigned short*)(ws + (2u << 20));       // 2 MiB
    unsigned short* kbuf = (unsigned short*)(ws + (4u << 20));       // 616 KiB
    unsigned short* vbuf = (unsigned short*)(ws + (5u << 20));       // 616 KiB
    unsigned short* qbuf = (unsigned short*)(ws + (6u << 20));       // 64 MiB (q, then attn in-place)
    unsigned short* vid_b = (unsigned short*)(ws + (70u << 20));     // 64 MiB video bf16

    k_cvt8<<<512, 256, 0, stream>>>(Wq, wq_b, 131072);
    k_cvt8<<<512, 256, 0, stream>>>(Wo, wo_b, 131072);

    dim3 gkv(3, 8, 2);  // ceil(308/128) x 1024/128 x {K,V}
    k_gemm_kv<<<gkv, 256, 0, stream>>>(text, Wk, Wv, kbuf, vbuf, Bn * TTn);

    k_cvt8<<<16384, 256, 0, stream>>>(video, vid_b, 4194304);

    k_gemm256<1><<<512, 512, 0, stream>>>(vid_b, wq_b, (void*)qbuf);

    dim3 ga(TVn / 128, Hn, Bn);  // 64 x 16 x 4
    k_attn2<<<ga, 256, 0, stream>>>(qbuf, kbuf, vbuf);

    k_gemm256<0><<<512, 512, 0, stream>>>(qbuf, wo_b, (void*)out);
}

// Round 7
// 377.042 us; speedup vs baseline: 1.0499x; 1.0499x over previous
//
#include <hip/hip_runtime.h>
#include <hip/hip_bf16.h>

// CrossAttention: B=4, Tv=8192, Tt=77, C=1024, H=16, D=64
// q = video@Wq.T ; k,v = text@W{k,v}.T ; softmax(qk^T/8)v ; out = attn@Wo.T
// Round 6: GEMMs reverted to proven 128x128 2-barrier kernel; attn v3 with
// swapped QK^T and fully in-register P (no P LDS, one barrier, 13.3 KB LDS).

typedef __attribute__((ext_vector_type(8))) short bf16x8;
typedef __attribute__((ext_vector_type(4))) float f32x4;
typedef __attribute__((ext_vector_type(8))) unsigned short u16x8;
typedef __attribute__((ext_vector_type(4))) unsigned short u16x4;

typedef const __attribute__((address_space(1))) void gv_t;
typedef __attribute__((address_space(3))) void lv_t;

static __device__ __forceinline__ unsigned short f2bf(float f) {
    union { float f; unsigned u; } v; v.f = f;
    unsigned r = v.u + 0x7FFFu + ((v.u >> 16) & 1u);  // RNE
    return (unsigned short)(r >> 16);
}

constexpr int Bn = 4, TVn = 8192, TTn = 77, Cn = 1024, Hn = 16;

// ---------------- fp32 -> bf16 convert, 8 elems/thread ----------------
__global__ void k_cvt8(const float* __restrict__ in, unsigned short* __restrict__ out, int n8) {
    int i = blockIdx.x * 256 + threadIdx.x;
    if (i >= n8) return;
    const float4* p = reinterpret_cast<const float4*>(in) + (size_t)i * 2;
    float4 a = p[0], b = p[1];
    u16x8 o = { f2bf(a.x), f2bf(a.y), f2bf(a.z), f2bf(a.w),
                f2bf(b.x), f2bf(b.y), f2bf(b.z), f2bf(b.w) };
    *reinterpret_cast<u16x8*>(out + (size_t)i * 8) = o;
}

// ---------------- unified bf16 GEMM: A[32768][1024] @ W[1024][1024]^T, 128x128 tiles ----------------
// XCD-swizzled flat grid (2048 blocks), N fastest; both-sides LDS segment swizzle. (round-2 proven)
template<int OUT_BF16>
__global__ __launch_bounds__(256)
void k_gemm_bb(const unsigned short* __restrict__ A, const unsigned short* __restrict__ Wb,
               void* __restrict__ outp) {
    __shared__ unsigned short As[128 * 32];
    __shared__ unsigned short Bs[128 * 32];
    const int tid = threadIdx.x, lane = tid & 63, wv = tid >> 6;
    const int orig = blockIdx.x;
    const int work = (orig & 7) * 256 + (orig >> 3);   // bijective XCD swizzle (2048 % 8 == 0)
    const int m0 = (work >> 3) * 128, n0 = (work & 7) * 128;
    const int wr = (wv >> 1) * 64, wc = (wv & 1) * 64;
    const int lr = lane & 15, lg = lane >> 4;
    const int brow = lane >> 2, bseg = lane & 3;
    f32x4 acc[4][4] = {};
    for (int kk = 0; kk < 1024; kk += 32) {
        #pragma unroll
        for (int j = 0; j < 2; ++j) {
            int chunk = wv * 2 + j;                  // 16 rows x 32 cols per 1 KiB chunk
            int trow = chunk * 16 + brow;
            int sseg = bseg ^ ((trow >> 1) & 3);     // pre-swizzled global source segment
            const unsigned short* ga = A + (size_t)(m0 + trow) * 1024 + kk + sseg * 8;
            __builtin_amdgcn_global_load_lds((gv_t*)ga, (lv_t*)&As[chunk * 512], 16, 0, 0);
            const unsigned short* gb = Wb + (size_t)(n0 + trow) * 1024 + kk + sseg * 8;
            __builtin_amdgcn_global_load_lds((gv_t*)gb, (lv_t*)&Bs[chunk * 512], 16, 0, 0);
        }
        __syncthreads();
        bf16x8 af[4], bfv[4];
        #pragma unroll
        for (int m = 0; m < 4; ++m) {
            int R = wr + m * 16 + lr;
            int seg = lg ^ ((R >> 1) & 3);           // matching read-side swizzle (2-way banks)
            af[m] = *reinterpret_cast<const bf16x8*>(&As[R * 32 + seg * 8]);
        }
        #pragma unroll
        for (int n = 0; n < 4; ++n) {
            int R = wc + n * 16 + lr;
            int seg = lg ^ ((R >> 1) & 3);
            bfv[n] = *reinterpret_cast<const bf16x8*>(&Bs[R * 32 + seg * 8]);
        }
        #pragma unroll
        for (int m = 0; m < 4; ++m)
            #pragma unroll
            for (int n = 0; n < 4; ++n)
                acc[m][n] = __builtin_amdgcn_mfma_f32_16x16x32_bf16(af[m], bfv[n], acc[m][n], 0, 0, 0);
        __syncthreads();
    }
    #pragma unroll
    for (int m = 0; m < 4; ++m)
        #pragma unroll
        for (int n = 0; n < 4; ++n)
            #pragma unroll
            for (int r = 0; r < 4; ++r) {
                int grow = m0 + wr + m * 16 + lg * 4 + r;
                int gcol = n0 + wc + n * 16 + lr;
                if (OUT_BF16) {
                    unsigned short bv = f2bf(acc[m][n][r]);
                    unsigned ov = __shfl_xor((unsigned)bv, 1);
                    if (!(lane & 1)) {
                        unsigned short* out = (unsigned short*)outp;
                        *reinterpret_cast<unsigned*>(out + (size_t)grow * 1024 + gcol) =
                            (unsigned)bv | (ov << 16);
                    }
                } else {
                    float v = acc[m][n][r];
                    float o = __shfl_xor(v, 1);
                    if (!(lane & 1)) {
                        float* out = (float*)outp;
                        float2 pv; pv.x = v; pv.y = o;
                        *reinterpret_cast<float2*>(out + (size_t)grow * 1024 + gcol) = pv;
                    }
                }
            }
}

// ---------------- K/V projection: A fp32 [M][1024] @ W fp32 [1024][1024]^T -> bf16 ----------------
__global__ __launch_bounds__(256)
void k_gemm_kv(const float* __restrict__ A, const float* __restrict__ W0,
               const float* __restrict__ W1, unsigned short* __restrict__ o0,
               unsigned short* __restrict__ o1, int M) {
    const float* W = blockIdx.z ? W1 : W0;
    unsigned short* out = blockIdx.z ? o1 : o0;
    __shared__ unsigned short As[128 * 32];
    __shared__ unsigned short Bs[128 * 32];
    const int tid = threadIdx.x, lane = tid & 63, wv = tid >> 6;
    const int m0 = blockIdx.x * 128, n0 = blockIdx.y * 128;
    const int wr = (wv >> 1) * 64, wc = (wv & 1) * 64;
    const int lr = lane & 15, lk = (lane >> 4) * 8, lg = lane >> 4;
    f32x4 acc[4][4] = {};
    for (int kk = 0; kk < 1024; kk += 32) {
        #pragma unroll
        for (int it = 0; it < 4; ++it) {
            int li = it * 256 + tid;
            int row = li >> 3, c4 = (li & 7) * 4;
            int gr = m0 + row;
            float4 v = make_float4(0.f, 0.f, 0.f, 0.f);
            if (gr < M) v = *reinterpret_cast<const float4*>(A + (size_t)gr * 1024 + kk + c4);
            u16x4 o = { f2bf(v.x), f2bf(v.y), f2bf(v.z), f2bf(v.w) };
            *reinterpret_cast<u16x4*>(&As[row * 32 + c4]) = o;
        }
        #pragma unroll
        for (int it = 0; it < 4; ++it) {
            int li = it * 256 + tid;
            int row = li >> 3, c4 = (li & 7) * 4;
            float4 v = *reinterpret_cast<const float4*>(W + (size_t)(n0 + row) * 1024 + kk + c4);
            u16x4 o = { f2bf(v.x), f2bf(v.y), f2bf(v.z), f2bf(v.w) };
            *reinterpret_cast<u16x4*>(&Bs[row * 32 + c4]) = o;
        }
        __syncthreads();
        bf16x8 af[4], bfv[4];
        #pragma unroll
        for (int m = 0; m < 4; ++m)
            af[m] = *reinterpret_cast<const bf16x8*>(&As[(wr + m * 16 + lr) * 32 + lk]);
        #pragma unroll
        for (int n = 0; n < 4; ++n)
            bfv[n] = *reinterpret_cast<const bf16x8*>(&Bs[(wc + n * 16 + lr) * 32 + lk]);
        #pragma unroll
        for (int m = 0; m < 4; ++m)
            #pragma unroll
            for (int n = 0; n < 4; ++n)
                acc[m][n] = __builtin_amdgcn_mfma_f32_16x16x32_bf16(af[m], bfv[n], acc[m][n], 0, 0, 0);
        __syncthreads();
    }
    #pragma unroll
    for (int m = 0; m < 4; ++m)
        #pragma unroll
        for (int n = 0; n < 4; ++n)
            #pragma unroll
            for (int r = 0; r < 4; ++r) {
                int grow = m0 + wr + m * 16 + lg * 4 + r;
                if (grow < M) {
                    int gcol = n0 + wc + n * 16 + lr;
                    out[(size_t)grow * 1024 + gcol] = f2bf(acc[m][n][r]);
                }
            }
}

// ---------------- attention v3: swapped QK^T, in-register P, LDS = V^T only ----------------
// Per block: 128 q-rows x 1 head. Per wave: 32 rows. One barrier (V^T staging).
// sc[mf][nf][r] (lane lg,lr) = S[t=16nf+4lg+r][qrow=wv*32+mf*16+lr]; softmax over lane's
// 20 k-values + 2 shfl_xor; P scaled by 1/sum, packed bf16 in regs, redistributed to the
// PV A-fragment layout by 8 bpermutes per (mf,ks):
//   fetched k = 32ks+16(lg>>1)+8(lg&1)+4(w>>1)+2(w&1)+{0,1} == target 32ks+8lg+2w+{0,1}.
__global__ __launch_bounds__(256)
void k_attn3(unsigned short* __restrict__ q,        // [32768][1024] bf16, attn written in-place
             const unsigned short* __restrict__ kb, // [308][1024]
             const unsigned short* __restrict__ vb) {
    constexpr int VP = 104;                          // 2-way-bank stride, 16B-aligned rows
    __shared__ unsigned short vt_s[64 * VP];         // 13312 B  V^T tile
    const int tid = threadIdx.x, lane = tid & 63, wv = tid >> 6;
    const int m0 = blockIdx.x * 128;
    const int h = blockIdx.y, b = blockIdx.z;
    const size_t qbase = ((size_t)b * TVn + m0) * Cn + h * 64;
    const size_t kvbase = (size_t)b * TTn * Cn + h * 64;
    const int lr = lane & 15, lg = lane >> 4;

    // stage V^T (coalesced reads, scatter LDS writes); t>=77 zeroed; cols 80..95 zeroed
    for (int li = tid; li < 80 * 64; li += 256) {
        int t = li >> 6, d = li & 63;
        unsigned short v = 0;
        if (t < 77) v = vb[kvbase + (size_t)t * Cn + d];
        vt_s[d * VP + t] = v;
    }
    for (int li = tid; li < 64 * 16; li += 256) {
        int d = li >> 4, t = 80 + (li & 15);
        vt_s[d * VP + t] = 0;
    }

    // QK^T, swapped operands: same fragments as before, mfma(K, Q) -> P^T layout
    f32x4 sc[2][5] = {};
    #pragma unroll
    for (int ks = 0; ks < 2; ++ks) {
        bf16x8 qa[2], kf[5];
        #pragma unroll
        for (int mf = 0; mf < 2; ++mf)
            qa[mf] = *reinterpret_cast<const bf16x8*>(
                q + qbase + (size_t)(wv * 32 + mf * 16 + lr) * Cn + ks * 32 + lg * 8);
        #pragma unroll
        for (int nf = 0; nf < 5; ++nf) {
            int t = nf * 16 + lr; if (t > 76) t = 76;   // clamp; masked in softmax
            kf[nf] = *reinterpret_cast<const bf16x8*>(
                kb + kvbase + (size_t)t * Cn + ks * 32 + lg * 8);
        }
        #pragma unroll
        for (int mf = 0; mf < 2; ++mf)
            #pragma unroll
            for (int nf = 0; nf < 5; ++nf)
                sc[mf][nf] = __builtin_amdgcn_mfma_f32_16x16x32_bf16(kf[nf], qa[mf], sc[mf][nf], 0, 0, 0);
    }

    // softmax per mf over lane's k = 16nf+4lg+r (mask k>=77: nf==4 && lg==3 && r>=1)
    unsigned pk[2][6][2];
    constexpr float CEXP = 0.125f * 1.44269504088896340736f;  // /sqrt(64) * log2(e)
    #pragma unroll
    for (int mf = 0; mf < 2; ++mf) {
        float mx = -1e30f;
        #pragma unroll
        for (int nf = 0; nf < 5; ++nf)
            #pragma unroll
            for (int r = 0; r < 4; ++r)
                if (!(nf == 4 && r >= 1)) mx = fmaxf(mx, sc[mf][nf][r]);
                else if (lg != 3)         mx = fmaxf(mx, sc[mf][nf][r]);
        mx = fmaxf(mx, __shfl_xor(mx, 16));
        mx = fmaxf(mx, __shfl_xor(mx, 32));
        float p[5][4];
        float sum = 0.f;
        #pragma unroll
        for (int nf = 0; nf < 5; ++nf)
            #pragma unroll
            for (int r = 0; r < 4; ++r) {
                bool valid = !(nf == 4 && lg == 3 && r >= 1);
                float pv = valid ? exp2f((sc[mf][nf][r] - mx) * CEXP) : 0.f;
                p[nf][r] = pv;
                sum += pv;
            }
        sum += __shfl_xor(sum, 16);
        sum += __shfl_xor(sum, 32);
        float inv = 1.f / sum;
        #pragma unroll
        for (int nf = 0; nf < 5; ++nf) {
            pk[mf][nf][0] = (unsigned)f2bf(p[nf][0] * inv) | ((unsigned)f2bf(p[nf][1] * inv) << 16);
            pk[mf][nf][1] = (unsigned)f2bf(p[nf][2] * inv) | ((unsigned)f2bf(p[nf][3] * inv) << 16);
        }
        pk[mf][5][0] = 0; pk[mf][5][1] = 0;   // k >= 80 zero-fill
    }

    __syncthreads();  // the ONLY barrier: vt_s staging visible

    // PV with in-register P redistribution
    f32x4 ovv[2][4] = {};
    const int sel = lg >> 1;
    const int srcA = ((lg & 1) * 2) * 16 + lr;       // source lane for dwords w=0,1
    const int srcB = ((lg & 1) * 2 + 1) * 16 + lr;   // source lane for dwords w=2,3
    #pragma unroll
    for (int ks = 0; ks < 3; ++ks) {
        bf16x8 vf[4];
        #pragma unroll
        for (int nf = 0; nf < 4; ++nf)
            vf[nf] = *reinterpret_cast<const bf16x8*>(
                &vt_s[(nf * 16 + lr) * VP + ks * 32 + lg * 8]);
        #pragma unroll
        for (int mf = 0; mf < 2; ++mf) {
            unsigned w0l = __shfl(pk[mf][ks * 2 + 0][0], srcA);
            unsigned w0h = __shfl(pk[mf][ks * 2 + 1][0], srcA);
            unsigned w1l = __shfl(pk[mf][ks * 2 + 0][1], srcA);
            unsigned w1h = __shfl(pk[mf][ks * 2 + 1][1], srcA);
            unsigned w2l = __shfl(pk[mf][ks * 2 + 0][0], srcB);
            unsigned w2h = __shfl(pk[mf][ks * 2 + 1][0], srcB);
            unsigned w3l = __shfl(pk[mf][ks * 2 + 0][1], srcB);
            unsigned w3h = __shfl(pk[mf][ks * 2 + 1][1], srcB);
            union { uint4 u; bf16x8 v; } pa;
            pa.u.x = sel ? w0h : w0l;
            pa.u.y = sel ? w1h : w1l;
            pa.u.z = sel ? w2h : w2l;
            pa.u.w = sel ? w3h : w3l;
            #pragma unroll
            for (int nf = 0; nf < 4; ++nf)
                ovv[mf][nf] = __builtin_amdgcn_mfma_f32_16x16x32_bf16(pa.v, vf[nf], ovv[mf][nf], 0, 0, 0);
        }
    }

    // write out (in-place over q): row = m0+wv*32+mf*16+lg*4+r, col = h*64+nf*16+lr
    #pragma unroll
    for (int mf = 0; mf < 2; ++mf)
        #pragma unroll
        for (int nf = 0; nf < 4; ++nf)
            #pragma unroll
            for (int r = 0; r < 4; ++r) {
                unsigned short bv = f2bf(ovv[mf][nf][r]);
                unsigned o = __shfl_xor((unsigned)bv, 1);
                if (!(lane & 1)) {
                    int row = m0 + wv * 32 + mf * 16 + lg * 4 + r;
                    int col = h * 64 + nf * 16 + lr;
                    *reinterpret_cast<unsigned*>(q + ((size_t)b * TVn + row) * Cn + col) =
                        (unsigned)bv | (o << 16);
                }
            }
}

extern "C" void kernel_launch(void* const* d_in, const int* in_sizes, int n_in,
                              void* d_out, int out_size, void* d_ws, size_t ws_size,
                              hipStream_t stream) {
    const float* video = (const float*)d_in[0];
    const float* text  = (const float*)d_in[1];
    const float* Wq = (const float*)d_in[2];
    const float* Wk = (const float*)d_in[3];
    const float* Wv = (const float*)d_in[4];
    const float* Wo = (const float*)d_in[5];
    float* out = (float*)d_out;

    char* ws = (char*)d_ws;
    unsigned short* wq_b = (unsigned short*)(ws);                    // 2 MiB
    unsigned short* wo_b = (unsigned short*)(ws + (2u << 20));       // 2 MiB
    unsigned short* kbuf = (unsigned short*)(ws + (4u << 20));       // 616 KiB
    unsigned short* vbuf = (unsigned short*)(ws + (5u << 20));       // 616 KiB
    unsigned short* qbuf = (unsigned short*)(ws + (6u << 20));       // 64 MiB (q, then attn in-place)
    unsigned short* vid_b = (unsigned short*)(ws + (70u << 20));     // 64 MiB video bf16

    k_cvt8<<<512, 256, 0, stream>>>(Wq, wq_b, 131072);
    k_cvt8<<<512, 256, 0, stream>>>(Wo, wo_b, 131072);

    dim3 gkv(3, 8, 2);  // ceil(308/128) x 1024/128 x {K,V}
    k_gemm_kv<<<gkv, 256, 0, stream>>>(text, Wk, Wv, kbuf, vbuf, Bn * TTn);

    k_cvt8<<<16384, 256, 0, stream>>>(video, vid_b, 4194304);

    k_gemm_bb<1><<<2048, 256, 0, stream>>>(vid_b, wq_b, (void*)qbuf);

    dim3 ga(TVn / 128, Hn, Bn);  // 64 x 16 x 4
    k_attn3<<<ga, 256, 0, stream>>>(qbuf, kbuf, vbuf);

    k_gemm_bb<0><<<2048, 256, 0, stream>>>(qbuf, wo_b, (void*)out);
}